// Round 8
// baseline (580.653 us; speedup 1.0000x reference)
//
#include <hip/hip_runtime.h>
#include <hip/hip_bf16.h>
#include <math.h>

// GLA cross-attention — round 8:
//  (a) attention: q-block 128, 32 q-rows/wave (2x16 tiles) -> 64 MFMA per 16
//      kf/vf fragment reads (2x arithmetic intensity vs r7); Q frags direct
//      from global (once per block); split-s=2 retained.
//  (b) gemm_mfma gains batch strides; 4x kv up-proj -> one grid.z=4 launch.
// Everything else byte-identical to PASSING round 7.
//
// ws float-offset map (top = 49,807,360 f = 199.2 MB):
//   attn_out_b u16 @ 0 | ml f32 @ 2,097,152 | Wot u16 @ f4,194,304
//   xkvb u16 @ 0 (dead after st9) | ckv f32 @ 8,388,608 (dead after st10)
//   Opart f32 @ 8,388,608 (aliases dead ckv)
//   xqb/WdQt/q_lat/q_lat_b/WuQt in 8,388,608..13,631,488 (dead pre-st9)
//   ckv_b u16 @ 16,777,216 | kvgb u16 @ 20,971,520 | vt u16 @ 37,748,736
//   qb u16 @ 46,137,344 | WdKVt u16 @ 48,234,496 | Wukvt u16 @ 49,283,072

typedef __attribute__((ext_vector_type(8))) short short8;
typedef __attribute__((ext_vector_type(4))) float f32x4;

__device__ __forceinline__ ushort f2bf(float x) {
    __hip_bfloat16 h = __float2bfloat16(x);
    return *reinterpret_cast<ushort*>(&h);
}

// ---------- elementwise fp32 -> bf16 cast (VERIFIED r6)
__global__ __launch_bounds__(256) void cast_bf16(const float* __restrict__ src,
        ushort* __restrict__ dst)
{
    size_t i = ((size_t)blockIdx.x * 256 + threadIdx.x) * 8;
    float4 a = *(const float4*)(src + i);
    float4 b = *(const float4*)(src + i + 4);
    ushort u[8] = {f2bf(a.x), f2bf(a.y), f2bf(a.z), f2bf(a.w),
                   f2bf(b.x), f2bf(b.y), f2bf(b.z), f2bf(b.w)};
    *(uint4*)(dst + i) = *(uint4*)u;
}

// ---------- transpose + cast (VERIFIED r6)
__global__ __launch_bounds__(256) void transpose_cast(const float* __restrict__ src,
        ushort* __restrict__ dst, int srl, int dstld, int remap,
        long src_z, long dst_z)
{
    __shared__ ushort tile[64][68];
    const int k0 = blockIdx.x * 64;
    const int n0 = blockIdx.y * 64;
    src += (size_t)blockIdx.z * src_z;
    dst += (size_t)blockIdx.z * dst_z;
    const int cb = n0 + (remap ? (n0 >> 7) * 64 : 0);
    const int t = threadIdx.x;
    {
        int r = t >> 4, c4 = t & 15;
        #pragma unroll
        for (int i = 0; i < 4; ++i) {
            float4 v = *(const float4*)(src + (size_t)(k0 + r + 16 * i) * srl + cb + c4 * 4);
            tile[r + 16 * i][c4 * 4 + 0] = f2bf(v.x);
            tile[r + 16 * i][c4 * 4 + 1] = f2bf(v.y);
            tile[r + 16 * i][c4 * 4 + 2] = f2bf(v.z);
            tile[r + 16 * i][c4 * 4 + 3] = f2bf(v.w);
        }
    }
    __syncthreads();
    {
        int n = t >> 4, k4 = t & 15;
        #pragma unroll
        for (int i = 0; i < 4; ++i) {
            ushort4 v;
            v.x = tile[k4 * 4 + 0][n + 16 * i];
            v.y = tile[k4 * 4 + 1][n + 16 * i];
            v.z = tile[k4 * 4 + 2][n + 16 * i];
            v.w = tile[k4 * 4 + 3][n + 16 * i];
            *(ushort4*)(dst + (size_t)(n0 + n + 16 * i) * dstld + k0 + k4 * 4) = v;
        }
    }
}

// ---------- MFMA bf16 GEMM (VERIFIED r6/r7) + batch strides (grid.z)
__global__ __launch_bounds__(256) void gemm_mfma(const ushort* __restrict__ A,
        const ushort* __restrict__ Bt, void* __restrict__ Cv,
        int M, int N, int K, int lda, int ldb, int ldc, int obf16, float scale,
        long strA, long strB, long strC)
{
    __shared__ ushort As[128][72];
    __shared__ ushort Bs[128][72];
    const int tid = threadIdx.x;
    const int w = tid >> 6, lane = tid & 63;
    const int quad = lane >> 4, l16 = lane & 15;
    const int wm = (w >> 1) * 64, wn = (w & 1) * 64;
    const int m0 = blockIdx.y * 128, n0 = blockIdx.x * 128;
    A  += (size_t)blockIdx.z * strA;
    Bt += (size_t)blockIdx.z * strB;

    f32x4 acc[4][4];
    #pragma unroll
    for (int i = 0; i < 4; ++i)
        #pragma unroll
        for (int j = 0; j < 4; ++j) acc[i][j] = (f32x4){0.f, 0.f, 0.f, 0.f};

    const int str = tid >> 3;
    const int stc = (tid & 7) * 8;

    for (int k0 = 0; k0 < K; k0 += 64) {
        __syncthreads();
        #pragma unroll
        for (int i = 0; i < 4; ++i) {
            int r = str + 32 * i;
            *(uint4*)&As[r][stc] = *(const uint4*)(A + (size_t)(m0 + r) * lda + k0 + stc);
            *(uint4*)&Bs[r][stc] = *(const uint4*)(Bt + (size_t)(n0 + r) * ldb + k0 + stc);
        }
        __syncthreads();
        #pragma unroll
        for (int kc = 0; kc < 2; ++kc) {
            short8 af[4], bf[4];
            #pragma unroll
            for (int i = 0; i < 4; ++i) {
                af[i] = *(const short8*)&As[wm + i * 16 + l16][kc * 32 + quad * 8];
                bf[i] = *(const short8*)&Bs[wn + i * 16 + l16][kc * 32 + quad * 8];
            }
            #pragma unroll
            for (int i = 0; i < 4; ++i)
                #pragma unroll
                for (int j = 0; j < 4; ++j)
                    acc[i][j] = __builtin_amdgcn_mfma_f32_16x16x32_bf16(af[i], bf[j], acc[i][j], 0, 0, 0);
        }
    }
    if (!obf16) {
        float* C = (float*)Cv + (size_t)blockIdx.z * strC;
        #pragma unroll
        for (int i = 0; i < 4; ++i)
            #pragma unroll
            for (int r = 0; r < 4; ++r) {
                float* cp = C + (size_t)(m0 + wm + i * 16 + quad * 4 + r) * ldc + n0 + wn + l16;
                #pragma unroll
                for (int j = 0; j < 4; ++j) cp[j * 16] = acc[i][j][r] * scale;
            }
    } else {
        ushort* C = (ushort*)Cv + (size_t)blockIdx.z * strC;
        #pragma unroll
        for (int i = 0; i < 4; ++i)
            #pragma unroll
            for (int r = 0; r < 4; ++r) {
                ushort* cp = C + (size_t)(m0 + wm + i * 16 + quad * 4 + r) * ldc + n0 + wn + l16;
                #pragma unroll
                for (int j = 0; j < 4; ++j) cp[j * 16] = f2bf(acc[i][j][r] * scale);
            }
    }
}

// ---------- coalesced rmsnorm, 512 cols, wave/row (VERIFIED r7)
__global__ __launch_bounds__(256) void rms_q_wave(const float* __restrict__ x,
        const float* __restrict__ w, ushort* __restrict__ dst)
{
    const int row = blockIdx.x * 4 + (threadIdx.x >> 6);
    const int lane = threadIdx.x & 63;
    const float* p = x + (size_t)row * 512;
    float4 v0 = *(const float4*)(p + lane * 4);
    float4 v1 = *(const float4*)(p + 256 + lane * 4);
    float ss = v0.x*v0.x + v0.y*v0.y + v0.z*v0.z + v0.w*v0.w
             + v1.x*v1.x + v1.y*v1.y + v1.z*v1.z + v1.w*v1.w;
    #pragma unroll
    for (int m = 1; m < 64; m <<= 1) ss += __shfl_xor(ss, m);
    float inv = rsqrtf(ss * (1.f / 512.f) + 1e-6f);
    float4 w0 = *(const float4*)(w + lane * 4);
    float4 w1 = *(const float4*)(w + 256 + lane * 4);
    ushort* dp = dst + (size_t)row * 512;
    ushort4 o0, o1;
    o0.x = f2bf(v0.x * inv * w0.x); o0.y = f2bf(v0.y * inv * w0.y);
    o0.z = f2bf(v0.z * inv * w0.z); o0.w = f2bf(v0.w * inv * w0.w);
    o1.x = f2bf(v1.x * inv * w1.x); o1.y = f2bf(v1.y * inv * w1.y);
    o1.z = f2bf(v1.z * inv * w1.z); o1.w = f2bf(v1.w * inv * w1.w);
    *(ushort4*)(dp + lane * 4)       = o0;
    *(ushort4*)(dp + 256 + lane * 4) = o1;
}

// ---------- coalesced grouped rmsnorm (VERIFIED r7)
__global__ __launch_bounds__(256) void rms_kv_wave(const float* __restrict__ x,
        const float* __restrict__ w, ushort* __restrict__ dst)
{
    const int idx = blockIdx.x * 4 + (threadIdx.x >> 6);
    const int lane = threadIdx.x & 63;
    const int r = idx >> 2, g = idx & 3;
    const float* p = x + (size_t)r * 1024 + g * 256;
    float4 v = *(const float4*)(p + lane * 4);
    float ss = v.x*v.x + v.y*v.y + v.z*v.z + v.w*v.w;
    #pragma unroll
    for (int m = 1; m < 64; m <<= 1) ss += __shfl_xor(ss, m);
    float inv = rsqrtf(ss * (1.f / 256.f) + 1e-6f);
    float4 wv = *(const float4*)(w + g * 256 + lane * 4);
    ushort4 o;
    o.x = f2bf(v.x * inv * wv.x); o.y = f2bf(v.y * inv * wv.y);
    o.z = f2bf(v.z * inv * wv.z); o.w = f2bf(v.w * inv * wv.w);
    *(ushort4*)(dst + (size_t)r * 1024 + g * 256 + lane * 4) = o;
}

// ---------- V transpose (VERIFIED r5/r6/r7)
__global__ __launch_bounds__(256) void transpose_v(const ushort* __restrict__ KVb,
                                                   ushort* __restrict__ Vt)
{
    __shared__ ushort tile[64][66];
    const int s0 = blockIdx.x * 64;
    const int d0 = blockIdx.y * 64;
    const int bh = blockIdx.z;
    const int b = bh >> 4, h = bh & 15, g = h >> 2, p = h & 3;
    const int t = threadIdx.x;
    const ushort* src = KVb + (size_t)g * 8388608ull + (size_t)(b * 4096) * 1024 + p * 256 + 128;
    {
        int sl = t >> 4, c4 = t & 15;
        #pragma unroll
        for (int i = 0; i < 4; ++i) {
            int s = sl + 16 * i;
            ushort4 v = *(const ushort4*)(src + (size_t)(s0 + s) * 1024 + d0 + c4 * 4);
            tile[s][c4 * 4 + 0] = v.x; tile[s][c4 * 4 + 1] = v.y;
            tile[s][c4 * 4 + 2] = v.z; tile[s][c4 * 4 + 3] = v.w;
        }
    }
    __syncthreads();
    {
        int dl = t >> 4, s4 = t & 15;
        ushort* dst = Vt + (size_t)(b * 16 + h) * 128 * 4096;
        #pragma unroll
        for (int i = 0; i < 4; ++i) {
            int d = dl + 16 * i;
            ushort4 v;
            v.x = tile[s4 * 4 + 0][d]; v.y = tile[s4 * 4 + 1][d];
            v.z = tile[s4 * 4 + 2][d]; v.w = tile[s4 * 4 + 3][d];
            *(ushort4*)(dst + (size_t)(d0 + d) * 4096 + s0 + s4 * 4) = v;
        }
    }
}

// ---------- MFMA flash attention, split-s=2, q-block 128, 32 q-rows/wave.
// grid (8, 16, 4): z = b*2 + chunk. Unnormalized fp32 partials + (m,l).
__global__ __launch_bounds__(256) void attn_mfma_split(const ushort* __restrict__ Qb,
        const ushort* __restrict__ KVb, const ushort* __restrict__ Vt,
        float* __restrict__ Opart, float* __restrict__ ml)
{
    __shared__ ushort Ks[64][136];
    __shared__ ushort VsT[128][72];
    __shared__ ushort Ps[4][32][72];

    const int q0 = blockIdx.x * 128;
    const int h = blockIdx.y;
    const int b = blockIdx.z >> 1, chunk = blockIdx.z & 1;
    const int g = h >> 2, p = h & 3;
    const int tid = threadIdx.x;
    const int w = tid >> 6, lane = tid & 63;
    const int quad = lane >> 4, l16 = lane & 15;
    const int sbase = chunk * 2048;

    const ushort* qg = Qb + (size_t)(b * 1024 + q0) * 2048 + h * 128;
    const ushort* kg = KVb + (size_t)g * 8388608ull + (size_t)(b * 4096 + sbase) * 1024 + p * 256;
    const ushort* vg = Vt + (size_t)(b * 16 + h) * 128 * 4096 + sbase;

    // Q A-fragments direct from global (once per block): wave w rows w*32+qt*16+l16
    short8 qf[2][4];
    #pragma unroll
    for (int qt = 0; qt < 2; ++qt)
        #pragma unroll
        for (int kc = 0; kc < 4; ++kc)
            qf[qt][kc] = *(const short8*)(qg + (size_t)(w * 32 + qt * 16 + l16) * 2048
                                          + kc * 32 + quad * 8);

    f32x4 accO[2][8];
    float m_i[2][4], l_i[2][4];
    #pragma unroll
    for (int qt = 0; qt < 2; ++qt) {
        #pragma unroll
        for (int dt = 0; dt < 8; ++dt) accO[qt][dt] = (f32x4){0.f, 0.f, 0.f, 0.f};
        #pragma unroll
        for (int r = 0; r < 4; ++r) { m_i[qt][r] = -INFINITY; l_i[qt][r] = 0.f; }
    }

    for (int s0 = 0; s0 < 2048; s0 += 64) {
        __syncthreads();
        {
            int r = tid >> 4, c8 = tid & 15;
            #pragma unroll
            for (int i = 0; i < 4; ++i)
                *(uint4*)&Ks[r + 16 * i][c8 * 8] =
                    *(const uint4*)(kg + (size_t)(s0 + r + 16 * i) * 1024 + c8 * 8);
            int d = tid >> 3, s8 = tid & 7;
            #pragma unroll
            for (int i = 0; i < 4; ++i)
                *(uint4*)&VsT[d + 32 * i][s8 * 8] =
                    *(const uint4*)(vg + (size_t)(d + 32 * i) * 4096 + s0 + s8 * 8);
        }
        __syncthreads();
        // S = Q K^T: kf shared across both q-tiles (2x MFMA per fragment read)
        f32x4 accS[2][4];
        #pragma unroll
        for (int qt = 0; qt < 2; ++qt)
            #pragma unroll
            for (int st = 0; st < 4; ++st) accS[qt][st] = (f32x4){0.f, 0.f, 0.f, 0.f};
        #pragma unroll
        for (int kc = 0; kc < 4; ++kc) {
            short8 kf[4];
            #pragma unroll
            for (int st = 0; st < 4; ++st)
                kf[st] = *(const short8*)&Ks[st * 16 + l16][kc * 32 + quad * 8];
            #pragma unroll
            for (int qt = 0; qt < 2; ++qt)
                #pragma unroll
                for (int st = 0; st < 4; ++st)
                    accS[qt][st] = __builtin_amdgcn_mfma_f32_16x16x32_bf16(qf[qt][kc], kf[st], accS[qt][st], 0, 0, 0);
        }
        // online softmax (rows quad*4+r of each q-tile; reduce over 16 s-lanes)
        #pragma unroll
        for (int qt = 0; qt < 2; ++qt)
            #pragma unroll
            for (int r = 0; r < 4; ++r) {
                float tm = fmaxf(fmaxf(accS[qt][0][r], accS[qt][1][r]),
                                 fmaxf(accS[qt][2][r], accS[qt][3][r]));
                #pragma unroll
                for (int msk = 1; msk < 16; msk <<= 1) tm = fmaxf(tm, __shfl_xor(tm, msk));
                float mn = fmaxf(m_i[qt][r], tm);
                float alpha = __expf(m_i[qt][r] - mn);
                float rs = 0.f;
                #pragma unroll
                for (int st = 0; st < 4; ++st) {
                    float e = __expf(accS[qt][st][r] - mn);
                    rs += e;
                    Ps[w][qt * 16 + quad * 4 + r][st * 16 + l16] = f2bf(e);
                }
                #pragma unroll
                for (int msk = 1; msk < 16; msk <<= 1) rs += __shfl_xor(rs, msk);
                l_i[qt][r] = l_i[qt][r] * alpha + rs;
                m_i[qt][r] = mn;
                #pragma unroll
                for (int dt = 0; dt < 8; ++dt) accO[qt][dt][r] *= alpha;
            }
        __syncthreads();
        // O += P V: vf shared across both q-tiles
        #pragma unroll
        for (int sc = 0; sc < 2; ++sc) {
            short8 pf[2];
            #pragma unroll
            for (int qt = 0; qt < 2; ++qt)
                pf[qt] = *(const short8*)&Ps[w][qt * 16 + l16][sc * 32 + quad * 8];
            #pragma unroll
            for (int dt = 0; dt < 8; ++dt) {
                short8 vf = *(const short8*)&VsT[dt * 16 + l16][sc * 32 + quad * 8];
                #pragma unroll
                for (int qt = 0; qt < 2; ++qt)
                    accO[qt][dt] = __builtin_amdgcn_mfma_f32_16x16x32_bf16(pf[qt], vf, accO[qt][dt], 0, 0, 0);
            }
        }
    }
    // epilogue: unnormalized fp32 partials + (m,l)
    #pragma unroll
    for (int qt = 0; qt < 2; ++qt) {
        const int qrow = q0 + w * 32 + qt * 16 + quad * 4;
        float* ob = Opart + (size_t)((chunk * 2 + b) * 1024 + qrow) * 2048 + h * 128 + l16;
        #pragma unroll
        for (int r = 0; r < 4; ++r)
            #pragma unroll
            for (int dt = 0; dt < 8; ++dt)
                ob[(size_t)r * 2048 + dt * 16] = accO[qt][dt][r];
        if (l16 == 0) {
            #pragma unroll
            for (int r = 0; r < 4; ++r) {
                size_t mi = ((size_t)((chunk * 2 + b) * 1024 + qrow + r) * 16 + h) * 2;
                ml[mi] = m_i[qt][r];
                ml[mi + 1] = l_i[qt][r];
            }
        }
    }
}

// ---------- merge the 2 s-chunks (VERIFIED r7)
__global__ __launch_bounds__(256) void attn_merge(const float* __restrict__ Opart,
        const float* __restrict__ ml, ushort* __restrict__ Om)
{
    const int idx = blockIdx.x * 4 + (threadIdx.x >> 6);
    const int lane = threadIdx.x & 63;
    const int h = idx & 15;
    const int q = (idx >> 4) & 1023;
    const int b = idx >> 14;

    size_t m1i = ((size_t)((0 * 2 + b) * 1024 + q) * 16 + h) * 2;
    size_t m2i = ((size_t)((1 * 2 + b) * 1024 + q) * 16 + h) * 2;
    float m1 = ml[m1i], l1 = ml[m1i + 1];
    float m2 = ml[m2i], l2 = ml[m2i + 1];
    float M = fmaxf(m1, m2);
    float w1 = __expf(m1 - M), w2 = __expf(m2 - M);
    float invL = 1.f / (l1 * w1 + l2 * w2);

    const float* o1 = Opart + (size_t)((0 * 2 + b) * 1024 + q) * 2048 + h * 128;
    const float* o2 = Opart + (size_t)((1 * 2 + b) * 1024 + q) * 2048 + h * 128;
    ushort* ob = Om + (size_t)(b * 1024 + q) * 2048 + h * 128;
    ob[lane]      = f2bf((o1[lane]      * w1 + o2[lane]      * w2) * invL);
    ob[lane + 64] = f2bf((o1[lane + 64] * w1 + o2[lane + 64] * w2) * invL);
}

extern "C" void kernel_launch(void* const* d_in, const int* in_sizes, int n_in,
                              void* d_out, int out_size, void* d_ws, size_t ws_size,
                              hipStream_t stream)
{
    (void)in_sizes; (void)n_in; (void)out_size; (void)ws_size;
    const float* x_q       = (const float*)d_in[0];
    const float* x_kv      = (const float*)d_in[1];
    const float* W_dQ      = (const float*)d_in[2];
    const float* q_norm_w  = (const float*)d_in[3];
    const float* W_uQ      = (const float*)d_in[4];
    const float* W_dKV     = (const float*)d_in[5];
    const float* kv_norm_w = (const float*)d_in[6];
    const float* W_ukv     = (const float*)d_in[7];
    const float* W_o       = (const float*)d_in[8];
    float* out = (float*)d_out;

    float* ws = (float*)d_ws;
    ushort* xkvb       = (ushort*)ws;
    ushort* attn_out_b = (ushort*)ws;
    float*  mlbuf      = ws + 2097152ull;
    ushort* Wot        = (ushort*)(ws + 4194304ull);
    float*  ckv        = ws + 8388608ull;
    float*  Opart      = ws + 8388608ull;                 // aliases dead ckv
    ushort* xqb        = (ushort*)(ws + 8388608ull);      // pre-stage-9 only
    ushort* WdQt       = (ushort*)(ws + 10485760ull);
    float*  q_lat      = ws + 11010048ull;
    ushort* q_lat_b    = (ushort*)(ws + 12058624ull);
    ushort* WuQt       = (ushort*)(ws + 12582912ull);
    ushort* ckv_b      = (ushort*)(ws + 16777216ull);
    ushort* kvgb       = (ushort*)(ws + 20971520ull);
    ushort* vt         = (ushort*)(ws + 37748736ull);
    ushort* qb         = (ushort*)(ws + 46137344ull);
    ushort* WdKVt      = (ushort*)(ws + 48234496ull);
    ushort* Wukvt      = (ushort*)(ws + 49283072ull);

    const float qscale = 0.08838834764831845f;            // 1/sqrt(128)

    // 1-3) q_lat = bf16(x_q) @ bf16(W_dQ)
    cast_bf16<<<2048, 256, 0, stream>>>(x_q, xqb);
    transpose_cast<<<dim3(32, 8, 1), 256, 0, stream>>>(W_dQ, WdQt, 512, 2048, 0, 0, 0);
    gemm_mfma<<<dim3(4, 16), 256, 0, stream>>>(xqb, WdQt, q_lat, 2048, 512, 2048, 2048, 2048, 512, 0, 1.f, 0, 0, 0);
    // 4) rmsnorm -> bf16
    rms_q_wave<<<512, 256, 0, stream>>>(q_lat, q_norm_w, q_lat_b);
    // 5-6) qb = (q_lat_b @ W_uQ[:, head :128]) * qscale
    transpose_cast<<<dim3(8, 32, 1), 256, 0, stream>>>(W_uQ, WuQt, 3072, 512, 1, 0, 0);
    gemm_mfma<<<dim3(16, 16), 256, 0, stream>>>(q_lat_b, WuQt, qb, 2048, 2048, 512, 512, 512, 2048, 1, qscale, 0, 0, 0);
    // 7-9) ckv = bf16(x_kv) @ bf16(W_dKV[:, :1024])
    cast_bf16<<<8192, 256, 0, stream>>>(x_kv, xkvb);
    transpose_cast<<<dim3(32, 16, 1), 256, 0, stream>>>(W_dKV, WdKVt, 1088, 2048, 0, 0, 0);
    gemm_mfma<<<dim3(8, 64), 256, 0, stream>>>(xkvb, WdKVt, ckv, 8192, 1024, 2048, 2048, 2048, 1024, 0, 1.f, 0, 0, 0);
    // 10) grouped rmsnorm -> bf16
    rms_kv_wave<<<8192, 256, 0, stream>>>(ckv, kv_norm_w, ckv_b);
    // 11-12) kv up-projection, single batched launch (z = group)
    transpose_cast<<<dim3(4, 16, 4), 256, 0, stream>>>(W_ukv, Wukvt, 1024, 256, 0, 262144, 262144);
    gemm_mfma<<<dim3(8, 64, 4), 256, 0, stream>>>(ckv_b, Wukvt, kvgb,
                                                  8192, 1024, 256, 1024, 256, 1024, 1, 1.f,
                                                  256, 262144, 8388608);
    // 13) V transpose
    transpose_v<<<dim3(64, 2, 32), 256, 0, stream>>>(kvgb, vt);
    // 14) split-s MFMA flash attention + merge
    attn_mfma_split<<<dim3(8, 16, 4), 256, 0, stream>>>(qb, kvgb, vt, Opart, mlbuf);
    attn_merge<<<8192, 256, 0, stream>>>(Opart, mlbuf, attn_out_b);
    // 15-16) out = attn_out_b @ bf16(W_o)
    transpose_cast<<<dim3(32, 32, 1), 256, 0, stream>>>(W_o, Wot, 2048, 2048, 0, 0, 0);
    gemm_mfma<<<dim3(16, 16), 256, 0, stream>>>(attn_out_b, Wot, out, 2048, 2048, 2048, 2048, 2048, 2048, 0, 1.f, 0, 0, 0);
}

// Round 9
// 567.916 us; speedup vs baseline: 1.0224x; 1.0224x over previous
//
#include <hip/hip_runtime.h>
#include <hip/hip_bf16.h>
#include <math.h>

// GLA cross-attention — round 9:
//  (a) attention REVERTED to r7-verified kernel (r8's 32-rows/wave regressed:
//      VGPR 136 / LDS 54KB -> occupancy 11%, latency-bound).
//  (b) gemm_mfma staging rewritten with global_load_lds width=16 (m97 ladder
//      step, 517->874 TF): unpadded LDS [128][64], wave-uniform dest + lane*16.
//  (c) batched kv up-proj launch kept from r8.
//
// ws float-offset map (top = 49,807,360 f = 199.2 MB):
//   attn_out_b u16 @ 0 | ml f32 @ 2,097,152 | Wot u16 @ f4,194,304
//   xkvb u16 @ 0 (dead after st9) | ckv f32 @ 8,388,608 (dead after st10)
//   Opart f32 @ 8,388,608 (aliases dead ckv)
//   xqb/WdQt/q_lat/q_lat_b/WuQt in 8,388,608..13,631,488 (dead pre-st9)
//   ckv_b u16 @ 16,777,216 | kvgb u16 @ 20,971,520 | vt u16 @ 37,748,736
//   qb u16 @ 46,137,344 | WdKVt u16 @ 48,234,496 | Wukvt u16 @ 49,283,072

typedef __attribute__((ext_vector_type(8))) short short8;
typedef __attribute__((ext_vector_type(4))) float f32x4;

__device__ __forceinline__ ushort f2bf(float x) {
    __hip_bfloat16 h = __float2bfloat16(x);
    return *reinterpret_cast<ushort*>(&h);
}

// async global->LDS, 16 B per lane; LDS dest = wave-uniform base + lane*16
__device__ __forceinline__ void gl2lds16(const ushort* g, ushort* l) {
    __builtin_amdgcn_global_load_lds(
        (const __attribute__((address_space(1))) unsigned int*)g,
        (__attribute__((address_space(3))) unsigned int*)l, 16, 0, 0);
}

// ---------- elementwise fp32 -> bf16 cast (VERIFIED r6)
__global__ __launch_bounds__(256) void cast_bf16(const float* __restrict__ src,
        ushort* __restrict__ dst)
{
    size_t i = ((size_t)blockIdx.x * 256 + threadIdx.x) * 8;
    float4 a = *(const float4*)(src + i);
    float4 b = *(const float4*)(src + i + 4);
    ushort u[8] = {f2bf(a.x), f2bf(a.y), f2bf(a.z), f2bf(a.w),
                   f2bf(b.x), f2bf(b.y), f2bf(b.z), f2bf(b.w)};
    *(uint4*)(dst + i) = *(uint4*)u;
}

// ---------- transpose + cast (VERIFIED r6)
__global__ __launch_bounds__(256) void transpose_cast(const float* __restrict__ src,
        ushort* __restrict__ dst, int srl, int dstld, int remap,
        long src_z, long dst_z)
{
    __shared__ ushort tile[64][68];
    const int k0 = blockIdx.x * 64;
    const int n0 = blockIdx.y * 64;
    src += (size_t)blockIdx.z * src_z;
    dst += (size_t)blockIdx.z * dst_z;
    const int cb = n0 + (remap ? (n0 >> 7) * 64 : 0);
    const int t = threadIdx.x;
    {
        int r = t >> 4, c4 = t & 15;
        #pragma unroll
        for (int i = 0; i < 4; ++i) {
            float4 v = *(const float4*)(src + (size_t)(k0 + r + 16 * i) * srl + cb + c4 * 4);
            tile[r + 16 * i][c4 * 4 + 0] = f2bf(v.x);
            tile[r + 16 * i][c4 * 4 + 1] = f2bf(v.y);
            tile[r + 16 * i][c4 * 4 + 2] = f2bf(v.z);
            tile[r + 16 * i][c4 * 4 + 3] = f2bf(v.w);
        }
    }
    __syncthreads();
    {
        int n = t >> 4, k4 = t & 15;
        #pragma unroll
        for (int i = 0; i < 4; ++i) {
            ushort4 v;
            v.x = tile[k4 * 4 + 0][n + 16 * i];
            v.y = tile[k4 * 4 + 1][n + 16 * i];
            v.z = tile[k4 * 4 + 2][n + 16 * i];
            v.w = tile[k4 * 4 + 3][n + 16 * i];
            *(ushort4*)(dst + (size_t)(n0 + n + 16 * i) * dstld + k0 + k4 * 4) = v;
        }
    }
}

// ---------- MFMA bf16 GEMM, m97-style async staging.
// C[M,N] = A[M,K] @ Bt[N,K]^T, both k-contiguous. 128x128 tile, BK=64,
// unpadded LDS (global_load_lds requires contiguous lane*16 layout).
__global__ __launch_bounds__(256) void gemm_mfma(const ushort* __restrict__ A,
        const ushort* __restrict__ Bt, void* __restrict__ Cv,
        int M, int N, int K, int lda, int ldb, int ldc, int obf16, float scale,
        long strA, long strB, long strC)
{
    __shared__ ushort As[128 * 64];
    __shared__ ushort Bs[128 * 64];
    const int tid = threadIdx.x;
    const int w = tid >> 6, lane = tid & 63;
    const int quad = lane >> 4, l16 = lane & 15;
    const int wm = (w >> 1) * 64, wn = (w & 1) * 64;
    const int m0 = blockIdx.y * 128, n0 = blockIdx.x * 128;
    A  += (size_t)blockIdx.z * strA;
    Bt += (size_t)blockIdx.z * strB;

    f32x4 acc[4][4];
    #pragma unroll
    for (int i = 0; i < 4; ++i)
        #pragma unroll
        for (int j = 0; j < 4; ++j) acc[i][j] = (f32x4){0.f, 0.f, 0.f, 0.f};

    const int lr = lane >> 3;            // row within 8-row group
    const int lc = (lane & 7) * 8;       // col (ushorts); lane offset = lane*16 B

    for (int k0 = 0; k0 < K; k0 += 64) {
        __syncthreads();
        #pragma unroll
        for (int i = 0; i < 4; ++i) {    // wave w stages rows w*32+i*8 .. +7
            int r0 = w * 32 + i * 8;
            gl2lds16(A  + (size_t)(m0 + r0 + lr) * lda + k0 + lc, &As[r0 * 64]);
            gl2lds16(Bt + (size_t)(n0 + r0 + lr) * ldb + k0 + lc, &Bs[r0 * 64]);
        }
        __syncthreads();                 // drains vmcnt (global_load_lds) + barrier
        #pragma unroll
        for (int kc = 0; kc < 2; ++kc) {
            short8 af[4], bf[4];
            #pragma unroll
            for (int i = 0; i < 4; ++i) {
                af[i] = *(const short8*)&As[(wm + i * 16 + l16) * 64 + kc * 32 + quad * 8];
                bf[i] = *(const short8*)&Bs[(wn + i * 16 + l16) * 64 + kc * 32 + quad * 8];
            }
            #pragma unroll
            for (int i = 0; i < 4; ++i)
                #pragma unroll
                for (int j = 0; j < 4; ++j)
                    acc[i][j] = __builtin_amdgcn_mfma_f32_16x16x32_bf16(af[i], bf[j], acc[i][j], 0, 0, 0);
        }
    }
    if (!obf16) {
        float* C = (float*)Cv + (size_t)blockIdx.z * strC;
        #pragma unroll
        for (int i = 0; i < 4; ++i)
            #pragma unroll
            for (int r = 0; r < 4; ++r) {
                float* cp = C + (size_t)(m0 + wm + i * 16 + quad * 4 + r) * ldc + n0 + wn + l16;
                #pragma unroll
                for (int j = 0; j < 4; ++j) cp[j * 16] = acc[i][j][r] * scale;
            }
    } else {
        ushort* C = (ushort*)Cv + (size_t)blockIdx.z * strC;
        #pragma unroll
        for (int i = 0; i < 4; ++i)
            #pragma unroll
            for (int r = 0; r < 4; ++r) {
                ushort* cp = C + (size_t)(m0 + wm + i * 16 + quad * 4 + r) * ldc + n0 + wn + l16;
                #pragma unroll
                for (int j = 0; j < 4; ++j) cp[j * 16] = f2bf(acc[i][j][r] * scale);
            }
    }
}

// ---------- coalesced rmsnorm, 512 cols, wave/row (VERIFIED r7)
__global__ __launch_bounds__(256) void rms_q_wave(const float* __restrict__ x,
        const float* __restrict__ w, ushort* __restrict__ dst)
{
    const int row = blockIdx.x * 4 + (threadIdx.x >> 6);
    const int lane = threadIdx.x & 63;
    const float* p = x + (size_t)row * 512;
    float4 v0 = *(const float4*)(p + lane * 4);
    float4 v1 = *(const float4*)(p + 256 + lane * 4);
    float ss = v0.x*v0.x + v0.y*v0.y + v0.z*v0.z + v0.w*v0.w
             + v1.x*v1.x + v1.y*v1.y + v1.z*v1.z + v1.w*v1.w;
    #pragma unroll
    for (int m = 1; m < 64; m <<= 1) ss += __shfl_xor(ss, m);
    float inv = rsqrtf(ss * (1.f / 512.f) + 1e-6f);
    float4 w0 = *(const float4*)(w + lane * 4);
    float4 w1 = *(const float4*)(w + 256 + lane * 4);
    ushort* dp = dst + (size_t)row * 512;
    ushort4 o0, o1;
    o0.x = f2bf(v0.x * inv * w0.x); o0.y = f2bf(v0.y * inv * w0.y);
    o0.z = f2bf(v0.z * inv * w0.z); o0.w = f2bf(v0.w * inv * w0.w);
    o1.x = f2bf(v1.x * inv * w1.x); o1.y = f2bf(v1.y * inv * w1.y);
    o1.z = f2bf(v1.z * inv * w1.z); o1.w = f2bf(v1.w * inv * w1.w);
    *(ushort4*)(dp + lane * 4)       = o0;
    *(ushort4*)(dp + 256 + lane * 4) = o1;
}

// ---------- coalesced grouped rmsnorm (VERIFIED r7)
__global__ __launch_bounds__(256) void rms_kv_wave(const float* __restrict__ x,
        const float* __restrict__ w, ushort* __restrict__ dst)
{
    const int idx = blockIdx.x * 4 + (threadIdx.x >> 6);
    const int lane = threadIdx.x & 63;
    const int r = idx >> 2, g = idx & 3;
    const float* p = x + (size_t)r * 1024 + g * 256;
    float4 v = *(const float4*)(p + lane * 4);
    float ss = v.x*v.x + v.y*v.y + v.z*v.z + v.w*v.w;
    #pragma unroll
    for (int m = 1; m < 64; m <<= 1) ss += __shfl_xor(ss, m);
    float inv = rsqrtf(ss * (1.f / 256.f) + 1e-6f);
    float4 wv = *(const float4*)(w + g * 256 + lane * 4);
    ushort4 o;
    o.x = f2bf(v.x * inv * wv.x); o.y = f2bf(v.y * inv * wv.y);
    o.z = f2bf(v.z * inv * wv.z); o.w = f2bf(v.w * inv * wv.w);
    *(ushort4*)(dst + (size_t)r * 1024 + g * 256 + lane * 4) = o;
}

// ---------- V transpose (VERIFIED r5/r6/r7)
__global__ __launch_bounds__(256) void transpose_v(const ushort* __restrict__ KVb,
                                                   ushort* __restrict__ Vt)
{
    __shared__ ushort tile[64][66];
    const int s0 = blockIdx.x * 64;
    const int d0 = blockIdx.y * 64;
    const int bh = blockIdx.z;
    const int b = bh >> 4, h = bh & 15, g = h >> 2, p = h & 3;
    const int t = threadIdx.x;
    const ushort* src = KVb + (size_t)g * 8388608ull + (size_t)(b * 4096) * 1024 + p * 256 + 128;
    {
        int sl = t >> 4, c4 = t & 15;
        #pragma unroll
        for (int i = 0; i < 4; ++i) {
            int s = sl + 16 * i;
            ushort4 v = *(const ushort4*)(src + (size_t)(s0 + s) * 1024 + d0 + c4 * 4);
            tile[s][c4 * 4 + 0] = v.x; tile[s][c4 * 4 + 1] = v.y;
            tile[s][c4 * 4 + 2] = v.z; tile[s][c4 * 4 + 3] = v.w;
        }
    }
    __syncthreads();
    {
        int dl = t >> 4, s4 = t & 15;
        ushort* dst = Vt + (size_t)(b * 16 + h) * 128 * 4096;
        #pragma unroll
        for (int i = 0; i < 4; ++i) {
            int d = dl + 16 * i;
            ushort4 v;
            v.x = tile[s4 * 4 + 0][d]; v.y = tile[s4 * 4 + 1][d];
            v.z = tile[s4 * 4 + 2][d]; v.w = tile[s4 * 4 + 3][d];
            *(ushort4*)(dst + (size_t)(d0 + d) * 4096 + s0 + s4 * 4) = v;
        }
    }
}

// ---------- MFMA flash attention, split-s=2 (REVERTED to r7-verified version).
// grid (16, 16, 4): z = b*2 + chunk. Unnormalized fp32 partials + (m,l).
__global__ __launch_bounds__(256) void attn_mfma_split(const ushort* __restrict__ Qb,
        const ushort* __restrict__ KVb, const ushort* __restrict__ Vt,
        float* __restrict__ Opart, float* __restrict__ ml)
{
    __shared__ ushort Ks[64][136];
    __shared__ ushort VsT[128][72];
    __shared__ ushort Ps[4][16][72];

    const int q0 = blockIdx.x * 64;
    const int h = blockIdx.y;
    const int b = blockIdx.z >> 1, chunk = blockIdx.z & 1;
    const int g = h >> 2, p = h & 3;
    const int tid = threadIdx.x;
    const int w = tid >> 6, lane = tid & 63;
    const int quad = lane >> 4, l16 = lane & 15;
    const int sbase = chunk * 2048;

    const ushort* qg = Qb + (size_t)(b * 1024 + q0) * 2048 + h * 128;
    const ushort* kg = KVb + (size_t)g * 8388608ull + (size_t)(b * 4096 + sbase) * 1024 + p * 256;
    const ushort* vg = Vt + (size_t)(b * 16 + h) * 128 * 4096 + sbase;

    {
        int r = tid >> 4, c8 = tid & 15;
        #pragma unroll
        for (int i = 0; i < 4; ++i)
            *(uint4*)&Ks[r + 16 * i][c8 * 8] =
                *(const uint4*)(qg + (size_t)(r + 16 * i) * 2048 + c8 * 8);
    }
    __syncthreads();
    short8 qf[4];
    {
        int qr = w * 16 + l16;
        #pragma unroll
        for (int kc = 0; kc < 4; ++kc)
            qf[kc] = *(const short8*)&Ks[qr][kc * 32 + quad * 8];
    }

    f32x4 accO[8];
    float m_i[4], l_i[4];
    #pragma unroll
    for (int dt = 0; dt < 8; ++dt) accO[dt] = (f32x4){0.f, 0.f, 0.f, 0.f};
    #pragma unroll
    for (int r = 0; r < 4; ++r) { m_i[r] = -INFINITY; l_i[r] = 0.f; }

    for (int s0 = 0; s0 < 2048; s0 += 64) {
        __syncthreads();
        {
            int r = tid >> 4, c8 = tid & 15;
            #pragma unroll
            for (int i = 0; i < 4; ++i)
                *(uint4*)&Ks[r + 16 * i][c8 * 8] =
                    *(const uint4*)(kg + (size_t)(s0 + r + 16 * i) * 1024 + c8 * 8);
            int d = tid >> 3, s8 = tid & 7;
            #pragma unroll
            for (int i = 0; i < 4; ++i)
                *(uint4*)&VsT[d + 32 * i][s8 * 8] =
                    *(const uint4*)(vg + (size_t)(d + 32 * i) * 4096 + s0 + s8 * 8);
        }
        __syncthreads();
        f32x4 accS[4];
        #pragma unroll
        for (int st = 0; st < 4; ++st) accS[st] = (f32x4){0.f, 0.f, 0.f, 0.f};
        #pragma unroll
        for (int kc = 0; kc < 4; ++kc) {
            #pragma unroll
            for (int st = 0; st < 4; ++st) {
                short8 kf = *(const short8*)&Ks[st * 16 + l16][kc * 32 + quad * 8];
                accS[st] = __builtin_amdgcn_mfma_f32_16x16x32_bf16(qf[kc], kf, accS[st], 0, 0, 0);
            }
        }
        #pragma unroll
        for (int r = 0; r < 4; ++r) {
            float tm = fmaxf(fmaxf(accS[0][r], accS[1][r]), fmaxf(accS[2][r], accS[3][r]));
            #pragma unroll
            for (int msk = 1; msk < 16; msk <<= 1) tm = fmaxf(tm, __shfl_xor(tm, msk));
            float mn = fmaxf(m_i[r], tm);
            float alpha = __expf(m_i[r] - mn);
            float rs = 0.f;
            #pragma unroll
            for (int st = 0; st < 4; ++st) {
                float e = __expf(accS[st][r] - mn);
                rs += e;
                Ps[w][quad * 4 + r][st * 16 + l16] = f2bf(e);
            }
            #pragma unroll
            for (int msk = 1; msk < 16; msk <<= 1) rs += __shfl_xor(rs, msk);
            l_i[r] = l_i[r] * alpha + rs;
            m_i[r] = mn;
            #pragma unroll
            for (int dt = 0; dt < 8; ++dt) accO[dt][r] *= alpha;
        }
        __syncthreads();
        short8 pf[2];
        #pragma unroll
        for (int sc = 0; sc < 2; ++sc)
            pf[sc] = *(const short8*)&Ps[w][l16][sc * 32 + quad * 8];
        #pragma unroll
        for (int sc = 0; sc < 2; ++sc) {
            #pragma unroll
            for (int dt = 0; dt < 8; ++dt) {
                short8 vf = *(const short8*)&VsT[dt * 16 + l16][sc * 32 + quad * 8];
                accO[dt] = __builtin_amdgcn_mfma_f32_16x16x32_bf16(pf[sc], vf, accO[dt], 0, 0, 0);
            }
        }
    }
    const int qrow = q0 + w * 16 + quad * 4;
    float* ob = Opart + (size_t)((chunk * 2 + b) * 1024 + qrow) * 2048 + h * 128 + l16;
    #pragma unroll
    for (int r = 0; r < 4; ++r)
        #pragma unroll
        for (int dt = 0; dt < 8; ++dt)
            ob[(size_t)r * 2048 + dt * 16] = accO[dt][r];
    if (l16 == 0) {
        #pragma unroll
        for (int r = 0; r < 4; ++r) {
            size_t mi = ((size_t)((chunk * 2 + b) * 1024 + qrow + r) * 16 + h) * 2;
            ml[mi] = m_i[r];
            ml[mi + 1] = l_i[r];
        }
    }
}

// ---------- merge the 2 s-chunks (VERIFIED r7)
__global__ __launch_bounds__(256) void attn_merge(const float* __restrict__ Opart,
        const float* __restrict__ ml, ushort* __restrict__ Om)
{
    const int idx = blockIdx.x * 4 + (threadIdx.x >> 6);
    const int lane = threadIdx.x & 63;
    const int h = idx & 15;
    const int q = (idx >> 4) & 1023;
    const int b = idx >> 14;

    size_t m1i = ((size_t)((0 * 2 + b) * 1024 + q) * 16 + h) * 2;
    size_t m2i = ((size_t)((1 * 2 + b) * 1024 + q) * 16 + h) * 2;
    float m1 = ml[m1i], l1 = ml[m1i + 1];
    float m2 = ml[m2i], l2 = ml[m2i + 1];
    float M = fmaxf(m1, m2);
    float w1 = __expf(m1 - M), w2 = __expf(m2 - M);
    float invL = 1.f / (l1 * w1 + l2 * w2);

    const float* o1 = Opart + (size_t)((0 * 2 + b) * 1024 + q) * 2048 + h * 128;
    const float* o2 = Opart + (size_t)((1 * 2 + b) * 1024 + q) * 2048 + h * 128;
    ushort* ob = Om + (size_t)(b * 1024 + q) * 2048 + h * 128;
    ob[lane]      = f2bf((o1[lane]      * w1 + o2[lane]      * w2) * invL);
    ob[lane + 64] = f2bf((o1[lane + 64] * w1 + o2[lane + 64] * w2) * invL);
}

extern "C" void kernel_launch(void* const* d_in, const int* in_sizes, int n_in,
                              void* d_out, int out_size, void* d_ws, size_t ws_size,
                              hipStream_t stream)
{
    (void)in_sizes; (void)n_in; (void)out_size; (void)ws_size;
    const float* x_q       = (const float*)d_in[0];
    const float* x_kv      = (const float*)d_in[1];
    const float* W_dQ      = (const float*)d_in[2];
    const float* q_norm_w  = (const float*)d_in[3];
    const float* W_uQ      = (const float*)d_in[4];
    const float* W_dKV     = (const float*)d_in[5];
    const float* kv_norm_w = (const float*)d_in[6];
    const float* W_ukv     = (const float*)d_in[7];
    const float* W_o       = (const float*)d_in[8];
    float* out = (float*)d_out;

    float* ws = (float*)d_ws;
    ushort* xkvb       = (ushort*)ws;
    ushort* attn_out_b = (ushort*)ws;
    float*  mlbuf      = ws + 2097152ull;
    ushort* Wot        = (ushort*)(ws + 4194304ull);
    float*  ckv        = ws + 8388608ull;
    float*  Opart      = ws + 8388608ull;                 // aliases dead ckv
    ushort* xqb        = (ushort*)(ws + 8388608ull);      // pre-stage-9 only
    ushort* WdQt       = (ushort*)(ws + 10485760ull);
    float*  q_lat      = ws + 11010048ull;
    ushort* q_lat_b    = (ushort*)(ws + 12058624ull);
    ushort* WuQt       = (ushort*)(ws + 12582912ull);
    ushort* ckv_b      = (ushort*)(ws + 16777216ull);
    ushort* kvgb       = (ushort*)(ws + 20971520ull);
    ushort* vt         = (ushort*)(ws + 37748736ull);
    ushort* qb         = (ushort*)(ws + 46137344ull);
    ushort* WdKVt      = (ushort*)(ws + 48234496ull);
    ushort* Wukvt      = (ushort*)(ws + 49283072ull);

    const float qscale = 0.08838834764831845f;            // 1/sqrt(128)

    // 1-3) q_lat = bf16(x_q) @ bf16(W_dQ)
    cast_bf16<<<2048, 256, 0, stream>>>(x_q, xqb);
    transpose_cast<<<dim3(32, 8, 1), 256, 0, stream>>>(W_dQ, WdQt, 512, 2048, 0, 0, 0);
    gemm_mfma<<<dim3(4, 16), 256, 0, stream>>>(xqb, WdQt, q_lat, 2048, 512, 2048, 2048, 2048, 512, 0, 1.f, 0, 0, 0);
    // 4) rmsnorm -> bf16
    rms_q_wave<<<512, 256, 0, stream>>>(q_lat, q_norm_w, q_lat_b);
    // 5-6) qb = (q_lat_b @ W_uQ[:, head :128]) * qscale
    transpose_cast<<<dim3(8, 32, 1), 256, 0, stream>>>(W_uQ, WuQt, 3072, 512, 1, 0, 0);
    gemm_mfma<<<dim3(16, 16), 256, 0, stream>>>(q_lat_b, WuQt, qb, 2048, 2048, 512, 512, 512, 2048, 1, qscale, 0, 0, 0);
    // 7-9) ckv = bf16(x_kv) @ bf16(W_dKV[:, :1024])
    cast_bf16<<<8192, 256, 0, stream>>>(x_kv, xkvb);
    transpose_cast<<<dim3(32, 16, 1), 256, 0, stream>>>(W_dKV, WdKVt, 1088, 2048, 0, 0, 0);
    gemm_mfma<<<dim3(8, 64), 256, 0, stream>>>(xkvb, WdKVt, ckv, 8192, 1024, 2048, 2048, 2048, 1024, 0, 1.f, 0, 0, 0);
    // 10) grouped rmsnorm -> bf16
    rms_kv_wave<<<8192, 256, 0, stream>>>(ckv, kv_norm_w, ckv_b);
    // 11-12) kv up-projection, single batched launch (z = group)
    transpose_cast<<<dim3(4, 16, 4), 256, 0, stream>>>(W_ukv, Wukvt, 1024, 256, 0, 262144, 262144);
    gemm_mfma<<<dim3(8, 64, 4), 256, 0, stream>>>(ckv_b, Wukvt, kvgb,
                                                  8192, 1024, 256, 1024, 256, 1024, 1, 1.f,
                                                  256, 262144, 8388608);
    // 13) V transpose
    transpose_v<<<dim3(64, 2, 32), 256, 0, stream>>>(kvgb, vt);
    // 14) split-s MFMA flash attention + merge
    attn_mfma_split<<<dim3(16, 16, 4), 256, 0, stream>>>(qb, kvgb, vt, Opart, mlbuf);
    attn_merge<<<8192, 256, 0, stream>>>(Opart, mlbuf, attn_out_b);
    // 15-16) out = attn_out_b @ bf16(W_o)
    transpose_cast<<<dim3(32, 32, 1), 256, 0, stream>>>(W_o, Wot, 2048, 2048, 0, 0, 0);
    gemm_mfma<<<dim3(16, 16), 256, 0, stream>>>(attn_out_b, Wot, out, 2048, 2048, 2048, 2048, 2048, 2048, 0, 1.f, 0, 0, 0);
}